// Round 1
// baseline (1018.704 us; speedup 1.0000x reference)
//
#include <hip/hip_runtime.h>
#include <stdint.h>

#define D 256
#define K 1024
#define NROWS 65536
#define BM 64
#define BK 64
#define LDW 260  // 256 + 4 pad: keeps float4 alignment (1040B rows) and breaks bank-conflict power-of-2 stride

// Bitwise replication of numpy's pairwise summation of a[i] = fl32(q[i]*q[i])
// over 128 contiguous floats: 8 accumulators stride-8, then the fixed combine tree.
__device__ __forceinline__ float np_block128_sumsq(const float* __restrict__ q) {
  float r[8];
#pragma unroll
  for (int j = 0; j < 8; ++j) r[j] = __fmul_rn(q[j], q[j]);
#pragma unroll
  for (int i = 8; i < 128; i += 8) {
#pragma unroll
    for (int j = 0; j < 8; ++j) r[j] = __fadd_rn(r[j], __fmul_rn(q[i + j], q[i + j]));
  }
  float t01 = __fadd_rn(r[0], r[1]);
  float t23 = __fadd_rn(r[2], r[3]);
  float t45 = __fadd_rn(r[4], r[5]);
  float t67 = __fadd_rn(r[6], r[7]);
  return __fadd_rn(__fadd_rn(t01, t23), __fadd_rn(t45, t67));
}

// numpy pairwise for n=256: sum(first 128) + sum(second 128)
__device__ __forceinline__ float np_sumsq256(const float* __restrict__ q) {
  return __fadd_rn(np_block128_sumsq(q), np_block128_sumsq(q + 128));
}

__global__ void c2_kernel(const float* __restrict__ cb, float* __restrict__ c2) {
  int k = blockIdx.x * blockDim.x + threadIdx.x;
  if (k < K) c2[k] = np_sumsq256(cb + (size_t)k * D);
}

__global__ __launch_bounds__(256) void vq_main(const float* __restrict__ z,
                                               const float* __restrict__ cb,
                                               const float* __restrict__ c2,
                                               float* __restrict__ out) {
  __shared__ float zs[BM][LDW];
  __shared__ float cs[BK][LDW];
  __shared__ float srow[BM];
  __shared__ int bidx[BM];

  const int tid = threadIdx.x;
  const int tx = tid & 15;   // code group 0..15
  const int ty = tid >> 4;   // row group 0..15
  const int r0 = blockIdx.x * BM;

  // ---- stage z tile (coalesced float4) ----
#pragma unroll
  for (int it = 0; it < 16; ++it) {
    int g = tid + it * 256;          // 0..4095 float4 slots
    int row = g >> 6, f4 = g & 63;
    float4 v = *reinterpret_cast<const float4*>(z + (size_t)(r0 + row) * D + f4 * 4);
    *reinterpret_cast<float4*>(&zs[row][f4 * 4]) = v;
  }
  __syncthreads();

  // ---- s = ||x||^2 per row, exact numpy pairwise order ----
  if (tid < BM) srow[tid] = np_sumsq256(&zs[tid][0]);
  // (made visible by the loop-top __syncthreads below before first use)

  float bd[4];
  int bi[4];
#pragma unroll
  for (int j = 0; j < 4; ++j) { bd[j] = 3.4e38f; bi[j] = 0x7fffffff; }

  for (int t = 0; t < K / BK; ++t) {
    __syncthreads();  // prev-iter cs readers done (and srow visible on t=0)
    // ---- stage c tile ----
#pragma unroll
    for (int it = 0; it < 16; ++it) {
      int g = tid + it * 256;
      int row = g >> 6, f4 = g & 63;
      float4 v = *reinterpret_cast<const float4*>(cb + (size_t)(t * BK + row) * D + f4 * 4);
      *reinterpret_cast<float4*>(&cs[row][f4 * 4]) = v;
    }
    __syncthreads();

    // ---- 4x4 micro-tile dot products, fp64 accumulation (== exact) ----
    double acc[4][4];
#pragma unroll
    for (int j = 0; j < 4; ++j)
#pragma unroll
      for (int i = 0; i < 4; ++i) acc[j][i] = 0.0;

#pragma unroll 2
    for (int d = 0; d < D; d += 4) {
      float4 a[4], b[4];
#pragma unroll
      for (int j = 0; j < 4; ++j) a[j] = *reinterpret_cast<const float4*>(&zs[ty + 16 * j][d]);
#pragma unroll
      for (int i = 0; i < 4; ++i) b[i] = *reinterpret_cast<const float4*>(&cs[tx + 16 * i][d]);
#pragma unroll
      for (int j = 0; j < 4; ++j)
#pragma unroll
        for (int i = 0; i < 4; ++i) {
          acc[j][i] += (double)a[j].x * (double)b[i].x;
          acc[j][i] += (double)a[j].y * (double)b[i].y;
          acc[j][i] += (double)a[j].z * (double)b[i].z;
          acc[j][i] += (double)a[j].w * (double)b[i].w;
        }
    }

    // ---- dist = fl32(fl32(s + c2_k) - fl32(2*m)), running argmin (first-index ties) ----
#pragma unroll
    for (int j = 0; j < 4; ++j) {
      const int row = ty + 16 * j;
      const float s = srow[row];
#pragma unroll
      for (int i = 0; i < 4; ++i) {
        const int k = t * BK + tx + 16 * i;  // ascending in i => first-min kept by strict <
        const float m = (float)acc[j][i];    // round exact dot to fp32 (closest to np's BLAS m)
        const float dist = __fsub_rn(__fadd_rn(s, c2[k]), __fmul_rn(2.0f, m));
        if (dist < bd[j]) { bd[j] = dist; bi[j] = k; }
      }
    }
  }

  __syncthreads();  // all dot-readers of cs done; safe to reuse cs as reduction scratch
  float* red_d = &cs[0][0];            // 1024 floats
  int* red_i = (int*)&cs[20][0];       // 1024 ints, disjoint region
#pragma unroll
  for (int j = 0; j < 4; ++j) {
    red_d[(ty + 16 * j) * 16 + tx] = bd[j];
    red_i[(ty + 16 * j) * 16 + tx] = bi[j];
  }
  __syncthreads();

  // ---- per-row reduction across the 16 code-groups; tie -> lowest index (np.argmin) ----
  if (tid < BM) {
    float best = red_d[tid * 16 + 0];
    int bsti = red_i[tid * 16 + 0];
    for (int x = 1; x < 16; ++x) {
      float d2 = red_d[tid * 16 + x];
      int i2 = red_i[tid * 16 + x];
      if (d2 < best || (d2 == best && i2 < bsti)) { best = d2; bsti = i2; }
    }
    bidx[tid] = bsti;
  }
  __syncthreads();

  // ---- epilogue: gather codes, z_q = fl32(z + fl32(c - z)), z_q_bar = c ----
  const int wid = tid >> 6, lane = tid & 63;
  float* out0 = out;
  float* out1 = out + (size_t)NROWS * D;
  for (int r = wid; r < BM; r += 4) {
    const int gr = r0 + r;
    const int kb = bidx[r];
    float4 c4 = *reinterpret_cast<const float4*>(cb + (size_t)kb * D + lane * 4);
    float4 z4 = *reinterpret_cast<const float4*>(&zs[r][lane * 4]);
    float4 q;
    q.x = __fadd_rn(z4.x, __fsub_rn(c4.x, z4.x));
    q.y = __fadd_rn(z4.y, __fsub_rn(c4.y, z4.y));
    q.z = __fadd_rn(z4.z, __fsub_rn(c4.z, z4.z));
    q.w = __fadd_rn(z4.w, __fsub_rn(c4.w, z4.w));
    *reinterpret_cast<float4*>(out0 + (size_t)gr * D + lane * 4) = q;
    *reinterpret_cast<float4*>(out1 + (size_t)gr * D + lane * 4) = c4;
  }
}

extern "C" void kernel_launch(void* const* d_in, const int* in_sizes, int n_in,
                              void* d_out, int out_size, void* d_ws, size_t ws_size,
                              hipStream_t stream) {
  const float* z = (const float*)d_in[0];
  const float* cb = (const float*)d_in[1];
  float* out = (float*)d_out;
  float* c2 = (float*)d_ws;  // 1024 floats of scratch, rewritten every call

  c2_kernel<<<K / 256, 256, 0, stream>>>(cb, c2);
  vq_main<<<NROWS / BM, 256, 0, stream>>>(z, cb, c2, out);
}

// Round 2
// 451.159 us; speedup vs baseline: 2.2580x; 2.2580x over previous
//
#include <hip/hip_runtime.h>
#include <stdint.h>

#define D 256
#define KCODES 1024
#define NROWS 65536

using short8 = __attribute__((ext_vector_type(8))) short;
using f32x4  = __attribute__((ext_vector_type(4))) float;

__device__ __forceinline__ float rne_f(float x) { return __builtin_rintf(x); }
__device__ __forceinline__ short f2bf(float x) { return (short)(__float_as_uint(x) >> 16); }

__device__ __forceinline__ void gl_lds16(const void* g, void* l) {
  __builtin_amdgcn_global_load_lds(
      (const __attribute__((address_space(1))) void*)g,
      (__attribute__((address_space(3))) void*)l, 16, 0, 0);
}

// ---------- numpy-exact pairwise sum of squares over 256 elements ----------
__device__ __forceinline__ float np_block128_sumsq(const float* __restrict__ q) {
  float r[8], v[8];
  *(float4*)(v) = *(const float4*)(q);
  *(float4*)(v + 4) = *(const float4*)(q + 4);
#pragma unroll
  for (int j = 0; j < 8; ++j) r[j] = __fmul_rn(v[j], v[j]);
  for (int i = 8; i < 128; i += 8) {
    *(float4*)(v) = *(const float4*)(q + i);
    *(float4*)(v + 4) = *(const float4*)(q + i + 4);
#pragma unroll
    for (int j = 0; j < 8; ++j) r[j] = __fadd_rn(r[j], __fmul_rn(v[j], v[j]));
  }
  float t01 = __fadd_rn(r[0], r[1]);
  float t23 = __fadd_rn(r[2], r[3]);
  float t45 = __fadd_rn(r[4], r[5]);
  float t67 = __fadd_rn(r[6], r[7]);
  return __fadd_rn(__fadd_rn(t01, t23), __fadd_rn(t45, t67));
}
__device__ __forceinline__ float np_sumsq256(const float* __restrict__ q) {
  return __fadd_rn(np_block128_sumsq(q), np_block128_sumsq(q + 128));
}

// prep1: srow[65536] and c2[1024], numpy-exact
__global__ void prep_sums(const float* __restrict__ z, const float* __restrict__ cb,
                          float* __restrict__ c2, float* __restrict__ srow) {
  int r = blockIdx.x * blockDim.x + threadIdx.x;
  if (r < NROWS) srow[r] = np_sumsq256(z + (size_t)r * D);
  else if (r < NROWS + KCODES) c2[r - NROWS] = np_sumsq256(cb + (size_t)(r - NROWS) * D);
}

// prep2: codebook -> 4 bf16 digit planes, bank-swizzled layout [j][n][k^swz]
__global__ void prep_cbdig(const float* __restrict__ cb, short* __restrict__ cbd) {
  int id = blockIdx.x * blockDim.x + threadIdx.x;  // 32768 threads
  int n = id >> 5, k8 = (id & 31) * 8;
  const float* src = cb + (size_t)n * D + k8;
  float v[8];
  *(float4*)(v) = *(const float4*)(src);
  *(float4*)(v + 4) = *(const float4*)(src + 4);
  short8 dig[4];
#pragma unroll
  for (int e = 0; e < 8; ++e) {
    float t = v[e] * 65536.0f;     // S_b = 16: |b|*2^16 <= 64
    float d0 = rne_f(t); t = __fmul_rn(__fsub_rn(t, d0), 256.0f);
    float d1 = rne_f(t); t = __fmul_rn(__fsub_rn(t, d1), 256.0f);
    float d2 = rne_f(t); t = __fmul_rn(__fsub_rn(t, d2), 256.0f);
    float d3 = rne_f(t);
    dig[0][e] = f2bf(d0); dig[1][e] = f2bf(d1); dig[2][e] = f2bf(d2); dig[3][e] = f2bf(d3);
  }
  int base_byte = n * 512 + ((k8 * 2) ^ ((n & 7) << 4));
#pragma unroll
  for (int j = 0; j < 4; ++j)
    *(short8*)((char*)cbd + (size_t)j * (KCODES * 512) + base_byte) = dig[j];
}

// ---------------- main MFMA kernel ----------------
#define BM 128
#define BN 32
#define NT (KCODES / BN)

#define MF(a, b, c) __builtin_amdgcn_mfma_f32_16x16x32_bf16((a), (b), (c), 0, 0, 0)

__global__ __launch_bounds__(512, 2) void vq_mfma(
    const float* __restrict__ z, const float* __restrict__ cb,
    const float* __restrict__ c2g, const float* __restrict__ srowg,
    const short* __restrict__ cbd, float* __restrict__ out) {
  __shared__ alignas(16) short bbuf[2][BN * D];  // 2 x 16 KB double-buffered B plane
  __shared__ float c2s[KCODES];
  __shared__ int bidx_s[BM];

  const int tid = threadIdx.x;
  const int lane = tid & 63;
  const int w = tid >> 6;  // wave 0..7, owns rows w*16..w*16+15
  const int r0 = blockIdx.x * BM;
  const int l15 = lane & 15, l4 = lane >> 4, l7 = lane & 7;

  // c2 -> LDS (lgkm path; keeps finalize off the vmcnt path)
  c2s[tid] = c2g[tid];
  c2s[tid + 512] = c2g[tid + 512];

  float sr[4];
#pragma unroll
  for (int r = 0; r < 4; ++r) sr[r] = srowg[r0 + w * 16 + l4 * 4 + r];

  // ---- A digits: global -> regs -> 4 balanced radix-256 bf16 digit planes ----
  short8 Adig[4][8];
  {
    const float* zr = z + (size_t)(r0 + w * 16 + l15) * D + l4 * 8;
#pragma unroll
    for (int f = 0; f < 8; ++f) {
      float v[8];
      *(float4*)(v) = *(const float4*)(zr + f * 32);
      *(float4*)(v + 4) = *(const float4*)(zr + f * 32 + 4);
#pragma unroll
      for (int e = 0; e < 8; ++e) {
        float t = v[e] * 16.0f;  // S_a = 4: |z|*16 <= ~90 < 128
        float d0 = rne_f(t); t = __fmul_rn(__fsub_rn(t, d0), 256.0f);
        float d1 = rne_f(t); t = __fmul_rn(__fsub_rn(t, d1), 256.0f);
        float d2 = rne_f(t); t = __fmul_rn(__fsub_rn(t, d2), 256.0f);
        float d3 = rne_f(t);
        Adig[0][f][e] = f2bf(d0); Adig[1][f][e] = f2bf(d1);
        Adig[2][f][e] = f2bf(d2); Adig[3][f][e] = f2bf(d3);
      }
    }
  }

  const char* cbd_b = (const char*)cbd;
#define STAGE(p) do { \
    int nt_ = (p) >> 2, j_ = (p) & 3; \
    const char* src_ = cbd_b + (size_t)j_ * (KCODES * 512) + (size_t)(nt_ * BN) * 512 + tid * 16; \
    char* dst_ = (char*)(&bbuf[(p) & 1][0]) + tid * 16; \
    gl_lds16(src_, dst_); gl_lds16(src_ + 8192, dst_ + 8192); \
  } while (0)

  float bd[4]; int bi[4];
#pragma unroll
  for (int r = 0; r < 4; ++r) { bd[r] = 3.4e38f; bi[r] = 0x7fffffff; }

  f32x4 acc[4][2];

  STAGE(0);
  __syncthreads();

  for (int nt = 0; nt < NT; ++nt) {
#pragma unroll
    for (int s = 0; s < 4; ++s) {
      f32x4 zz = {0.f, 0.f, 0.f, 0.f};
      acc[s][0] = zz; acc[s][1] = zz;
    }
    const int pbase = nt * 4;
#pragma unroll
    for (int j = 0; j < 4; ++j) {
      const int p = pbase + j;
      if (p + 1 < NT * 4) STAGE(p + 1);  // issue next plane into other buffer
      const char* buf = (const char*)&bbuf[p & 1][0];
#pragma unroll
      for (int f = 0; f < 8; ++f) {
        const int ko = (f * 64 + l4 * 16) ^ (l7 << 4);
        short8 B0 = *(const short8*)(buf + l15 * 512 + ko);
        short8 B1 = *(const short8*)(buf + (16 + l15) * 512 + ko);
        acc[j + 0][0] = MF(Adig[0][f], B0, acc[j + 0][0]);
        acc[j + 0][1] = MF(Adig[0][f], B1, acc[j + 0][1]);
        if (j < 3) { acc[j + 1][0] = MF(Adig[1][f], B0, acc[j + 1][0]);
                     acc[j + 1][1] = MF(Adig[1][f], B1, acc[j + 1][1]); }
        if (j < 2) { acc[j + 2][0] = MF(Adig[2][f], B0, acc[j + 2][0]);
                     acc[j + 2][1] = MF(Adig[2][f], B1, acc[j + 2][1]); }
        if (j < 1) { acc[j + 3][0] = MF(Adig[3][f], B0, acc[j + 3][0]);
                     acc[j + 3][1] = MF(Adig[3][f], B1, acc[j + 3][1]); }
      }
      __syncthreads();  // drains stage(p+1) loads AND all readers of bbuf[p&1]
    }
    // finalize this code-tile: recombine exact integer group sums in fp64
#pragma unroll
    for (int n = 0; n < 2; ++n) {
#pragma unroll
      for (int r = 0; r < 4; ++r) {
        double md = (double)acc[0][n][r] * 0x1p-20
                  + (double)acc[1][n][r] * 0x1p-28
                  + (double)acc[2][n][r] * 0x1p-36
                  + (double)acc[3][n][r] * 0x1p-44;
        float mf = (float)md;
        int kc = nt * BN + n * 16 + l15;
        float dist = __fsub_rn(__fadd_rn(sr[r], c2s[kc]), __fmul_rn(2.0f, mf));
        if (dist < bd[r]) { bd[r] = dist; bi[r] = kc; }  // ascending kc => first-min
      }
    }
  }

  // per-row argmin across the 16 lanes of each row group (np tie-break: lowest idx)
#pragma unroll
  for (int r = 0; r < 4; ++r) {
#pragma unroll
    for (int m = 1; m < 16; m <<= 1) {
      float od = __shfl_xor(bd[r], m);
      int oi = __shfl_xor(bi[r], m);
      if (od < bd[r] || (od == bd[r] && oi < bi[r])) { bd[r] = od; bi[r] = oi; }
    }
    if (l15 == 0) bidx_s[w * 16 + l4 * 4 + r] = bi[r];
  }
  __syncthreads();

  // epilogue: gather codes, z_q = fl(z + fl(c - z)), z_q_bar = c
  {
    const int row_l = tid >> 2, seg = tid & 3;
    const int grow = r0 + row_l;
    const int kb = bidx_s[row_l];
    const float* crow = cb + (size_t)kb * D;
    const float* zrow = z + (size_t)grow * D;
    float* o0 = out + (size_t)grow * D;
    float* o1 = out + (size_t)NROWS * D + (size_t)grow * D;
#pragma unroll
    for (int ii = 0; ii < 16; ++ii) {
      int q = seg * 16 + ii;
      float4 c4 = *(const float4*)(crow + q * 4);
      float4 z4 = *(const float4*)(zrow + q * 4);
      float4 o;
      o.x = __fadd_rn(z4.x, __fsub_rn(c4.x, z4.x));
      o.y = __fadd_rn(z4.y, __fsub_rn(c4.y, z4.y));
      o.z = __fadd_rn(z4.z, __fsub_rn(c4.z, z4.z));
      o.w = __fadd_rn(z4.w, __fsub_rn(c4.w, z4.w));
      *(float4*)(o0 + q * 4) = o;
      *(float4*)(o1 + q * 4) = c4;
    }
  }
}

// ---------------- round-1 fallback (exact fp64 dot) if ws is too small ----------------
__global__ void c2_kernel_fb(const float* __restrict__ cb, float* __restrict__ c2) {
  int k = blockIdx.x * blockDim.x + threadIdx.x;
  if (k < KCODES) c2[k] = np_sumsq256(cb + (size_t)k * D);
}

__global__ __launch_bounds__(256) void vq_fallback(const float* __restrict__ z,
                                                   const float* __restrict__ cb,
                                                   const float* __restrict__ c2,
                                                   float* __restrict__ out) {
  __shared__ float zs[64][260];
  __shared__ float cs[64][260];
  __shared__ float srow[64];
  __shared__ int bidx[64];
  const int tid = threadIdx.x;
  const int tx = tid & 15, ty = tid >> 4;
  const int r0 = blockIdx.x * 64;
#pragma unroll
  for (int it = 0; it < 16; ++it) {
    int g = tid + it * 256, row = g >> 6, f4 = g & 63;
    *(float4*)(&zs[row][f4 * 4]) = *(const float4*)(z + (size_t)(r0 + row) * D + f4 * 4);
  }
  __syncthreads();
  if (tid < 64) srow[tid] = np_sumsq256(&zs[tid][0]);
  float bd[4]; int bi[4];
#pragma unroll
  for (int j = 0; j < 4; ++j) { bd[j] = 3.4e38f; bi[j] = 0x7fffffff; }
  for (int t = 0; t < KCODES / 64; ++t) {
    __syncthreads();
#pragma unroll
    for (int it = 0; it < 16; ++it) {
      int g = tid + it * 256, row = g >> 6, f4 = g & 63;
      *(float4*)(&cs[row][f4 * 4]) = *(const float4*)(cb + (size_t)(t * 64 + row) * D + f4 * 4);
    }
    __syncthreads();
    double acc[4][4];
#pragma unroll
    for (int j = 0; j < 4; ++j)
#pragma unroll
      for (int i = 0; i < 4; ++i) acc[j][i] = 0.0;
#pragma unroll 2
    for (int d = 0; d < D; d += 4) {
      float4 a[4], b[4];
#pragma unroll
      for (int j = 0; j < 4; ++j) a[j] = *(const float4*)(&zs[ty + 16 * j][d]);
#pragma unroll
      for (int i = 0; i < 4; ++i) b[i] = *(const float4*)(&cs[tx + 16 * i][d]);
#pragma unroll
      for (int j = 0; j < 4; ++j)
#pragma unroll
        for (int i = 0; i < 4; ++i) {
          acc[j][i] += (double)a[j].x * (double)b[i].x;
          acc[j][i] += (double)a[j].y * (double)b[i].y;
          acc[j][i] += (double)a[j].z * (double)b[i].z;
          acc[j][i] += (double)a[j].w * (double)b[i].w;
        }
    }
#pragma unroll
    for (int j = 0; j < 4; ++j) {
      const float s = srow[ty + 16 * j];
#pragma unroll
      for (int i = 0; i < 4; ++i) {
        const int k = t * 64 + tx + 16 * i;
        const float m = (float)acc[j][i];
        const float dist = __fsub_rn(__fadd_rn(s, c2[k]), __fmul_rn(2.0f, m));
        if (dist < bd[j]) { bd[j] = dist; bi[j] = k; }
      }
    }
  }
  __syncthreads();
  float* red_d = &cs[0][0];
  int* red_i = (int*)&cs[20][0];
#pragma unroll
  for (int j = 0; j < 4; ++j) {
    red_d[(ty + 16 * j) * 16 + tx] = bd[j];
    red_i[(ty + 16 * j) * 16 + tx] = bi[j];
  }
  __syncthreads();
  if (tid < 64) {
    float best = red_d[tid * 16 + 0];
    int bsti = red_i[tid * 16 + 0];
    for (int x = 1; x < 16; ++x) {
      float d2 = red_d[tid * 16 + x]; int i2 = red_i[tid * 16 + x];
      if (d2 < best || (d2 == best && i2 < bsti)) { best = d2; bsti = i2; }
    }
    bidx[tid] = bsti;
  }
  __syncthreads();
  const int wid = tid >> 6, lane = tid & 63;
  float* out0 = out;
  float* out1 = out + (size_t)NROWS * D;
  for (int r = wid; r < 64; r += 4) {
    const int gr = r0 + r;
    const int kb = bidx[r];
    float4 c4 = *(const float4*)(cb + (size_t)kb * D + lane * 4);
    float4 z4 = *(const float4*)(&zs[r][lane * 4]);
    float4 q;
    q.x = __fadd_rn(z4.x, __fsub_rn(c4.x, z4.x));
    q.y = __fadd_rn(z4.y, __fsub_rn(c4.y, z4.y));
    q.z = __fadd_rn(z4.z, __fsub_rn(c4.z, z4.z));
    q.w = __fadd_rn(z4.w, __fsub_rn(c4.w, z4.w));
    *(float4*)(out0 + (size_t)gr * D + lane * 4) = q;
    *(float4*)(out1 + (size_t)gr * D + lane * 4) = c4;
  }
}

extern "C" void kernel_launch(void* const* d_in, const int* in_sizes, int n_in,
                              void* d_out, int out_size, void* d_ws, size_t ws_size,
                              hipStream_t stream) {
  const float* z = (const float*)d_in[0];
  const float* cb = (const float*)d_in[1];
  float* out = (float*)d_out;

  const size_t c2_off = 0;                 // 4 KB
  const size_t srow_off = 4096;            // 256 KB
  const size_t cbd_off = 4096 + 262144;    // 2 MB digit planes
  const size_t need = cbd_off + (size_t)4 * KCODES * 512;

  if (ws_size < need) {  // safety fallback: round-1 exact fp64 path
    float* c2 = (float*)d_ws;
    c2_kernel_fb<<<KCODES / 256, 256, 0, stream>>>(cb, c2);
    vq_fallback<<<NROWS / 64, 256, 0, stream>>>(z, cb, c2, out);
    return;
  }

  float* c2 = (float*)((char*)d_ws + c2_off);
  float* srow = (float*)((char*)d_ws + srow_off);
  short* cbd = (short*)((char*)d_ws + cbd_off);

  prep_sums<<<(NROWS + KCODES) / 256, 256, 0, stream>>>(z, cb, c2, srow);
  prep_cbdig<<<(KCODES * 32) / 256, 256, 0, stream>>>(cb, cbd);
  vq_mfma<<<NROWS / BM, 512, 0, stream>>>(z, cb, c2, srow, cbd, out);
}

// Round 3
// 368.839 us; speedup vs baseline: 2.7619x; 1.2232x over previous
//
#include <hip/hip_runtime.h>
#include <stdint.h>

#define D 256
#define KCODES 1024
#define NROWS 65536

using short8 = __attribute__((ext_vector_type(8))) short;
using f32x4  = __attribute__((ext_vector_type(4))) float;

__device__ __forceinline__ float rne_f(float x) { return __builtin_rintf(x); }
__device__ __forceinline__ short f2bf(float x) { return (short)(__float_as_uint(x) >> 16); }

__device__ __forceinline__ void gl_lds16(const void* g, void* l) {
  __builtin_amdgcn_global_load_lds(
      (const __attribute__((address_space(1))) void*)g,
      (__attribute__((address_space(3))) void*)l, 16, 0, 0);
}

// ---------- numpy-exact pairwise sum of squares over 256 elements ----------
__device__ __forceinline__ float np_block128_sumsq(const float* __restrict__ q) {
  float r[8], v[8];
  *(float4*)(v) = *(const float4*)(q);
  *(float4*)(v + 4) = *(const float4*)(q + 4);
#pragma unroll
  for (int j = 0; j < 8; ++j) r[j] = __fmul_rn(v[j], v[j]);
  for (int i = 8; i < 128; i += 8) {
    *(float4*)(v) = *(const float4*)(q + i);
    *(float4*)(v + 4) = *(const float4*)(q + i + 4);
#pragma unroll
    for (int j = 0; j < 8; ++j) r[j] = __fadd_rn(r[j], __fmul_rn(v[j], v[j]));
  }
  float t01 = __fadd_rn(r[0], r[1]);
  float t23 = __fadd_rn(r[2], r[3]);
  float t45 = __fadd_rn(r[4], r[5]);
  float t67 = __fadd_rn(r[6], r[7]);
  return __fadd_rn(__fadd_rn(t01, t23), __fadd_rn(t45, t67));
}
__device__ __forceinline__ float np_sumsq256(const float* __restrict__ q) {
  return __fadd_rn(np_block128_sumsq(q), np_block128_sumsq(q + 128));
}

// prep1: srow[65536] and c2[1024], numpy-exact
__global__ void prep_sums(const float* __restrict__ z, const float* __restrict__ cb,
                          float* __restrict__ c2, float* __restrict__ srow) {
  int r = blockIdx.x * blockDim.x + threadIdx.x;
  if (r < NROWS) srow[r] = np_sumsq256(z + (size_t)r * D);
  else if (r < NROWS + KCODES) c2[r - NROWS] = np_sumsq256(cb + (size_t)(r - NROWS) * D);
}

// prep2: codebook -> 4 bf16 digit planes, k-major tile layout so the main
// kernel's wave-level ds_read is a contiguous 1024B block (zero bank conflicts):
// plane j, code-tile nt (32 codes): 16KB tile laid out as
//   [f(0..7)][c16(0..1)][kgrp(0..3)][code(0..15)][8 bf16]
// where element k-range of a 16B chunk = f*32 + kgrp*8 .. +8.
__global__ void prep_cbdig(const float* __restrict__ cb, short* __restrict__ cbd) {
  int id = blockIdx.x * blockDim.x + threadIdx.x;  // 32768 threads
  int n = id >> 5, k8 = id & 31;
  const float* src = cb + (size_t)n * D + k8 * 8;
  float v[8];
  *(float4*)(v) = *(const float4*)(src);
  *(float4*)(v + 4) = *(const float4*)(src + 4);
  short8 dig[4];
#pragma unroll
  for (int e = 0; e < 8; ++e) {
    float t = v[e] * 65536.0f;     // S_b: |c|*2^16 <= 64, digit |.|<=128
    float d0 = rne_f(t); t = __fmul_rn(__fsub_rn(t, d0), 256.0f);
    float d1 = rne_f(t); t = __fmul_rn(__fsub_rn(t, d1), 256.0f);
    float d2 = rne_f(t); t = __fmul_rn(__fsub_rn(t, d2), 256.0f);
    float d3 = rne_f(t);
    dig[0][e] = f2bf(d0); dig[1][e] = f2bf(d1); dig[2][e] = f2bf(d2); dig[3][e] = f2bf(d3);
  }
  int nt = n >> 5, c = n & 31;
  int dst_byte = nt * 16384 + (k8 >> 2) * 2048 + (c >> 4) * 1024 + (k8 & 3) * 256 + (c & 15) * 16;
#pragma unroll
  for (int j = 0; j < 4; ++j)
    *(short8*)((char*)cbd + (size_t)j * (KCODES * 512) + dst_byte) = dig[j];
}

// ---------------- main MFMA kernel ----------------
#define BM 64
#define BN 32
#define NT (KCODES / BN)

#define MF(a, b, c) __builtin_amdgcn_mfma_f32_16x16x32_bf16((a), (b), (c), 0, 0, 0)

__global__ __launch_bounds__(256, 2) void vq_mfma(
    const float* __restrict__ z, const float* __restrict__ cb,
    const float* __restrict__ c2g, const float* __restrict__ srowg,
    const short* __restrict__ cbd, float* __restrict__ out) {
  __shared__ alignas(16) short bbuf[2][BN * D];  // 2 x 16 KB double-buffered B plane
  __shared__ float c2s[KCODES];
  __shared__ int bidx_s[BM];

  const int tid = threadIdx.x;
  const int lane = tid & 63;
  const int w = tid >> 6;  // wave 0..3, owns rows w*16..w*16+15
  const int r0 = blockIdx.x * BM;
  const int l15 = lane & 15, l4 = lane >> 4;

  c2s[tid] = c2g[tid];
  c2s[tid + 256] = c2g[tid + 256];
  c2s[tid + 512] = c2g[tid + 512];
  c2s[tid + 768] = c2g[tid + 768];

  float sr[4];
#pragma unroll
  for (int r = 0; r < 4; ++r) sr[r] = srowg[r0 + w * 16 + l4 * 4 + r];

  // ---- A digits: global -> regs -> 4 balanced radix-256 bf16 digit planes ----
  short8 Adig[4][8];
  {
    const float* zr = z + (size_t)(r0 + w * 16 + l15) * D + l4 * 8;
#pragma unroll
    for (int f = 0; f < 8; ++f) {
      float v[8];
      *(float4*)(v) = *(const float4*)(zr + f * 32);
      *(float4*)(v + 4) = *(const float4*)(zr + f * 32 + 4);
#pragma unroll
      for (int e = 0; e < 8; ++e) {
        float t = v[e] * 16.0f;  // S_a: |z|*16 <= ~90 < 128
        float d0 = rne_f(t); t = __fmul_rn(__fsub_rn(t, d0), 256.0f);
        float d1 = rne_f(t); t = __fmul_rn(__fsub_rn(t, d1), 256.0f);
        float d2 = rne_f(t); t = __fmul_rn(__fsub_rn(t, d2), 256.0f);
        float d3 = rne_f(t);
        Adig[0][f][e] = f2bf(d0); Adig[1][f][e] = f2bf(d1);
        Adig[2][f][e] = f2bf(d2); Adig[3][f][e] = f2bf(d3);
      }
    }
  }

  const char* cbd_b = (const char*)cbd;
#define STAGE(p) do { \
    int nt_ = (p) >> 2, j_ = (p) & 3; \
    const char* src_ = cbd_b + (size_t)j_ * (KCODES * 512) + (size_t)nt_ * 16384 + tid * 16; \
    char* dst_ = (char*)(&bbuf[(p) & 1][0]) + tid * 16; \
    gl_lds16(src_, dst_); gl_lds16(src_ + 4096, dst_ + 4096); \
    gl_lds16(src_ + 8192, dst_ + 8192); gl_lds16(src_ + 12288, dst_ + 12288); \
  } while (0)

  float bd[4]; int bi[4];
#pragma unroll
  for (int r = 0; r < 4; ++r) { bd[r] = 3.4e38f; bi[r] = 0x7fffffff; }

  f32x4 acc[4][2];

  STAGE(0);
  __syncthreads();

  for (int nt = 0; nt < NT; ++nt) {
#pragma unroll
    for (int s = 0; s < 4; ++s) {
      f32x4 zz = {0.f, 0.f, 0.f, 0.f};
      acc[s][0] = zz; acc[s][1] = zz;
    }
    const int pbase = nt * 4;
#pragma unroll
    for (int j = 0; j < 4; ++j) {
      const int p = pbase + j;
      if (p + 1 < NT * 4) STAGE(p + 1);  // issue next plane into other buffer
      const char* buf = (const char*)&bbuf[p & 1][0];
#pragma unroll
      for (int f = 0; f < 8; ++f) {
        // contiguous 1024B per wave per read: zero bank conflicts
        short8 B0 = *(const short8*)(buf + f * 2048 + lane * 16);
        short8 B1 = *(const short8*)(buf + f * 2048 + 1024 + lane * 16);
        acc[j + 0][0] = MF(Adig[0][f], B0, acc[j + 0][0]);
        acc[j + 0][1] = MF(Adig[0][f], B1, acc[j + 0][1]);
        if (j < 3) { acc[j + 1][0] = MF(Adig[1][f], B0, acc[j + 1][0]);
                     acc[j + 1][1] = MF(Adig[1][f], B1, acc[j + 1][1]); }
        if (j < 2) { acc[j + 2][0] = MF(Adig[2][f], B0, acc[j + 2][0]);
                     acc[j + 2][1] = MF(Adig[2][f], B1, acc[j + 2][1]); }
        if (j < 1) { acc[j + 3][0] = MF(Adig[3][f], B0, acc[j + 3][0]);
                     acc[j + 3][1] = MF(Adig[3][f], B1, acc[j + 3][1]); }
      }
      __syncthreads();  // drains stage(p+1) loads AND all readers of bbuf[p&1]
    }
    // finalize this code-tile: exact fp64 Horner recombination of integer group sums
#pragma unroll
    for (int n = 0; n < 2; ++n) {
#pragma unroll
      for (int r = 0; r < 4; ++r) {
        double md = fma(fma(fma((double)acc[3][n][r], 0x1p-8,
                                (double)acc[2][n][r]), 0x1p-8,
                            (double)acc[1][n][r]), 0x1p-8,
                        (double)acc[0][n][r]) * 0x1p-20;  // every step exact in fp64
        float mf = (float)md;
        int kc = nt * BN + n * 16 + l15;
        float dist = __fsub_rn(__fadd_rn(sr[r], c2s[kc]), __fmul_rn(2.0f, mf));
        if (dist < bd[r]) { bd[r] = dist; bi[r] = kc; }  // ascending kc => first-min
      }
    }
  }

  // per-row argmin across the 16 lanes of each row group (np tie-break: lowest idx)
#pragma unroll
  for (int r = 0; r < 4; ++r) {
#pragma unroll
    for (int m = 1; m < 16; m <<= 1) {
      float od = __shfl_xor(bd[r], m);
      int oi = __shfl_xor(bi[r], m);
      if (od < bd[r] || (od == bd[r] && oi < bi[r])) { bd[r] = od; bi[r] = oi; }
    }
    if (l15 == 0) bidx_s[w * 16 + l4 * 4 + r] = bi[r];
  }
  __syncthreads();

  // epilogue: gather codes, z_q = fl(z + fl(c - z)), z_q_bar = c
  {
    const int row_l = tid >> 2, seg = tid & 3;
    const int grow = r0 + row_l;
    const int kb = bidx_s[row_l];
    const float* crow = cb + (size_t)kb * D;
    const float* zrow = z + (size_t)grow * D;
    float* o0 = out + (size_t)grow * D;
    float* o1 = out + (size_t)NROWS * D + (size_t)grow * D;
#pragma unroll
    for (int ii = 0; ii < 16; ++ii) {
      int q = seg * 16 + ii;
      float4 c4 = *(const float4*)(crow + q * 4);
      float4 z4 = *(const float4*)(zrow + q * 4);
      float4 o;
      o.x = __fadd_rn(z4.x, __fsub_rn(c4.x, z4.x));
      o.y = __fadd_rn(z4.y, __fsub_rn(c4.y, z4.y));
      o.z = __fadd_rn(z4.z, __fsub_rn(c4.z, z4.z));
      o.w = __fadd_rn(z4.w, __fsub_rn(c4.w, z4.w));
      *(float4*)(o0 + q * 4) = o;
      *(float4*)(o1 + q * 4) = c4;
    }
  }
}

// ---------------- fallback (exact fp64 dot) if ws is too small ----------------
__global__ void c2_kernel_fb(const float* __restrict__ cb, float* __restrict__ c2) {
  int k = blockIdx.x * blockDim.x + threadIdx.x;
  if (k < KCODES) c2[k] = np_sumsq256(cb + (size_t)k * D);
}

__global__ __launch_bounds__(256) void vq_fallback(const float* __restrict__ z,
                                                   const float* __restrict__ cb,
                                                   const float* __restrict__ c2,
                                                   float* __restrict__ out) {
  __shared__ float zs[64][260];
  __shared__ float cs[64][260];
  __shared__ float srow[64];
  __shared__ int bidx[64];
  const int tid = threadIdx.x;
  const int tx = tid & 15, ty = tid >> 4;
  const int r0 = blockIdx.x * 64;
#pragma unroll
  for (int it = 0; it < 16; ++it) {
    int g = tid + it * 256, row = g >> 6, f4 = g & 63;
    *(float4*)(&zs[row][f4 * 4]) = *(const float4*)(z + (size_t)(r0 + row) * D + f4 * 4);
  }
  __syncthreads();
  if (tid < 64) srow[tid] = np_sumsq256(&zs[tid][0]);
  float bd[4]; int bi[4];
#pragma unroll
  for (int j = 0; j < 4; ++j) { bd[j] = 3.4e38f; bi[j] = 0x7fffffff; }
  for (int t = 0; t < KCODES / 64; ++t) {
    __syncthreads();
#pragma unroll
    for (int it = 0; it < 16; ++it) {
      int g = tid + it * 256, row = g >> 6, f4 = g & 63;
      *(float4*)(&cs[row][f4 * 4]) = *(const float4*)(cb + (size_t)(t * 64 + row) * D + f4 * 4);
    }
    __syncthreads();
    double acc[4][4];
#pragma unroll
    for (int j = 0; j < 4; ++j)
#pragma unroll
      for (int i = 0; i < 4; ++i) acc[j][i] = 0.0;
#pragma unroll 2
    for (int d = 0; d < D; d += 4) {
      float4 a[4], b[4];
#pragma unroll
      for (int j = 0; j < 4; ++j) a[j] = *(const float4*)(&zs[ty + 16 * j][d]);
#pragma unroll
      for (int i = 0; i < 4; ++i) b[i] = *(const float4*)(&cs[tx + 16 * i][d]);
#pragma unroll
      for (int j = 0; j < 4; ++j)
#pragma unroll
        for (int i = 0; i < 4; ++i) {
          acc[j][i] += (double)a[j].x * (double)b[i].x;
          acc[j][i] += (double)a[j].y * (double)b[i].y;
          acc[j][i] += (double)a[j].z * (double)b[i].z;
          acc[j][i] += (double)a[j].w * (double)b[i].w;
        }
    }
#pragma unroll
    for (int j = 0; j < 4; ++j) {
      const float s = srow[ty + 16 * j];
#pragma unroll
      for (int i = 0; i < 4; ++i) {
        const int k = t * 64 + tx + 16 * i;
        const float m = (float)acc[j][i];
        const float dist = __fsub_rn(__fadd_rn(s, c2[k]), __fmul_rn(2.0f, m));
        if (dist < bd[j]) { bd[j] = dist; bi[j] = k; }
      }
    }
  }
  __syncthreads();
  float* red_d = &cs[0][0];
  int* red_i = (int*)&cs[20][0];
#pragma unroll
  for (int j = 0; j < 4; ++j) {
    red_d[(ty + 16 * j) * 16 + tx] = bd[j];
    red_i[(ty + 16 * j) * 16 + tx] = bi[j];
  }
  __syncthreads();
  if (tid < 64) {
    float best = red_d[tid * 16 + 0];
    int bsti = red_i[tid * 16 + 0];
    for (int x = 1; x < 16; ++x) {
      float d2 = red_d[tid * 16 + x]; int i2 = red_i[tid * 16 + x];
      if (d2 < best || (d2 == best && i2 < bsti)) { best = d2; bsti = i2; }
    }
    bidx[tid] = bsti;
  }
  __syncthreads();
  const int wid = tid >> 6, lane = tid & 63;
  float* out0 = out;
  float* out1 = out + (size_t)NROWS * D;
  for (int r = wid; r < 64; r += 4) {
    const int gr = r0 + r;
    const int kb = bidx[r];
    float4 c4 = *(const float4*)(cb + (size_t)kb * D + lane * 4);
    float4 z4 = *(const float4*)(&zs[r][lane * 4]);
    float4 q;
    q.x = __fadd_rn(z4.x, __fsub_rn(c4.x, z4.x));
    q.y = __fadd_rn(z4.y, __fsub_rn(c4.y, z4.y));
    q.z = __fadd_rn(z4.z, __fsub_rn(c4.z, z4.z));
    q.w = __fadd_rn(z4.w, __fsub_rn(c4.w, z4.w));
    *(float4*)(out0 + (size_t)gr * D + lane * 4) = q;
    *(float4*)(out1 + (size_t)gr * D + lane * 4) = c4;
  }
}

extern "C" void kernel_launch(void* const* d_in, const int* in_sizes, int n_in,
                              void* d_out, int out_size, void* d_ws, size_t ws_size,
                              hipStream_t stream) {
  const float* z = (const float*)d_in[0];
  const float* cb = (const float*)d_in[1];
  float* out = (float*)d_out;

  const size_t c2_off = 0;                 // 4 KB
  const size_t srow_off = 4096;            // 256 KB
  const size_t cbd_off = 4096 + 262144;    // 2 MB digit planes
  const size_t need = cbd_off + (size_t)4 * KCODES * 512;

  if (ws_size < need) {  // safety fallback: exact fp64 path
    float* c2 = (float*)d_ws;
    c2_kernel_fb<<<KCODES / 256, 256, 0, stream>>>(cb, c2);
    vq_fallback<<<NROWS / 64, 256, 0, stream>>>(z, cb, c2, out);
    return;
  }

  float* c2 = (float*)((char*)d_ws + c2_off);
  float* srow = (float*)((char*)d_ws + srow_off);
  short* cbd = (short*)((char*)d_ws + cbd_off);

  prep_sums<<<(NROWS + KCODES) / 256, 256, 0, stream>>>(z, cb, c2, srow);
  prep_cbdig<<<(KCODES * 32) / 256, 256, 0, stream>>>(cb, cbd);
  vq_mfma<<<NROWS / BM, 256, 0, stream>>>(z, cb, c2, srow, cbd, out);
}